// Round 1
// baseline (1000.225 us; speedup 1.0000x reference)
//
#include <hip/hip_runtime.h>
#include <math.h>

// Problem constants (from reference)
#define N_NODES   100000
#define N_EDGES   1600000
#define NUM_RBF   128
#define NUM_GAUSS 32
#define NFEAT     160      // 128 + 32
#define CUTOFF    6.0f

#define EPB    64          // edges per block
#define BLOCK  256

__global__ __launch_bounds__(BLOCK) void edge_feat_kernel(
    const float* __restrict__ pos,     // [N_NODES, 3]
    const int*   __restrict__ eidx,    // [2, N_EDGES] (int32 per harness)
    float*       __restrict__ out)     // [N_EDGES, 160]
{
    __shared__ float s_d[EPB];   // dist
    __shared__ float s_c[EPB];   // cosine cutoff
    __shared__ float s_t[EPB];   // exp(-alpha*dist)

    const int blockEdge0 = blockIdx.x * EPB;
    const int tid = threadIdx.x;

    // Phase 1: per-edge scalars (threads 0..63)
    if (tid < EPB) {
        const int e = blockEdge0 + tid;
        const int s = eidx[e];
        const int t = eidx[N_EDGES + e];
        const float dx = pos[3*s + 0] - pos[3*t + 0];
        const float dy = pos[3*s + 1] - pos[3*t + 1];
        const float dz = pos[3*s + 2] - pos[3*t + 2];
        const float dist = sqrtf(dx*dx + dy*dy + dz*dz + 1e-12f);
        s_d[tid] = dist;
        const float c = 0.5f * (__cosf(dist * (float)(M_PI / 6.0)) + 1.0f);
        s_c[tid] = (dist < CUTOFF) ? c : 0.0f;
        s_t[tid] = __expf(-(5.0f / 6.0f) * dist);
    }
    __syncthreads();

    // Compile-time constants (double-precision folded)
    const float start = (float)0.0024787521766663585;           // exp(-6)
    const float mstep = (float)((1.0 - 0.0024787521766663585) / (NUM_RBF - 1));
    const float beta  = (float)(1.0 /
        ((2.0 / NUM_RBF * (1.0 - 0.0024787521766663585)) *
         (2.0 / NUM_RBF * (1.0 - 0.0024787521766663585))));     // ~4116.4
    const float gstep = (float)(10.0 / (NUM_GAUSS - 1));        // linspace(0,10,32)
    const float ginv  = 20.48f;                                 // 1/(2*width^2), width=0.15625

    // Phase 2: coalesced float4 output. 64 edges * 160 feats / 4 = 2560 float4.
    float4* out4 = (float4*)(out + (size_t)blockEdge0 * NFEAT);
    const int n4 = EPB * NFEAT / 4;   // 2560
    for (int i = tid; i < n4; i += BLOCK) {
        const int f4 = i * 4;
        const int e  = i / 40;              // f4 / 160
        const int f  = f4 - e * NFEAT;      // feature index of lane 0 of this vec
        const float d = s_d[e];
        float4 r;
        if (f < NUM_RBF) {
            const float c = s_c[e];
            const float t = s_t[e];
            #pragma unroll
            for (int j = 0; j < 4; ++j) {
                const float m = start + (float)(f + j) * mstep;
                const float u = t - m;
                ((float*)&r)[j] = c * __expf(-beta * u * u);
            }
        } else {
            const int g = f - NUM_RBF;
            #pragma unroll
            for (int j = 0; j < 4; ++j) {
                const float ctr = (float)(g + j) * gstep;
                const float u = d - ctr;
                ((float*)&r)[j] = __expf(-ginv * u * u);
            }
        }
        out4[i] = r;
    }
}

extern "C" void kernel_launch(void* const* d_in, const int* in_sizes, int n_in,
                              void* d_out, int out_size, void* d_ws, size_t ws_size,
                              hipStream_t stream) {
    const float* pos  = (const float*)d_in[0];
    const int*   eidx = (const int*)d_in[1];
    float*       out  = (float*)d_out;

    const int nblocks = N_EDGES / EPB;   // 1,600,000 / 64 = 25,000
    edge_feat_kernel<<<nblocks, BLOCK, 0, stream>>>(pos, eidx, out);
}

// Round 2
// 988.532 us; speedup vs baseline: 1.0118x; 1.0118x over previous
//
#include <hip/hip_runtime.h>
#include <math.h>

// Problem constants (from reference)
#define N_NODES   100000
#define N_EDGES   1600000
#define NUM_RBF   128
#define NUM_GAUSS 32
#define NFEAT     160      // 128 + 32 -> 40 float4 columns per edge
#define CUTOFF    6.0f

#define EPB    64          // edges per block
#define BLOCK  320         // 5 waves; 320/40 = 8 edges processed per iteration
#define COLS   40          // float4 columns per edge
#define EPI    (BLOCK/COLS) // 8 edges per iteration
#define NITER  (EPB/EPI)    // 8 iterations

static __device__ __forceinline__ float fast_exp2(float x) {
#if __has_builtin(__builtin_amdgcn_exp2f)
    return __builtin_amdgcn_exp2f(x);   // raw v_exp_f32 (D = 2^S0)
#else
    return __expf(0.6931471805599453f * x);
#endif
}

__global__ __launch_bounds__(BLOCK) void edge_feat_kernel(
    const float* __restrict__ pos,     // [N_NODES, 3]
    const int*   __restrict__ eidx,    // [2, N_EDGES]
    float*       __restrict__ out)     // [N_EDGES, 160]
{
    __shared__ float4 s_edge[EPB];     // (dist, cutoff, exp(-alpha*d), 0)

    const int blockEdge0 = blockIdx.x * EPB;
    const int tid = threadIdx.x;

    // ---- Phase 1: per-edge scalars (threads 0..63) ----
    if (tid < EPB) {
        const int e = blockEdge0 + tid;
        const int s = eidx[e];
        const int t = eidx[N_EDGES + e];
        const float dx = pos[3*s + 0] - pos[3*t + 0];
        const float dy = pos[3*s + 1] - pos[3*t + 1];
        const float dz = pos[3*s + 2] - pos[3*t + 2];
        const float dist = sqrtf(dx*dx + dy*dy + dz*dz + 1e-12f);
        const float c = 0.5f * (__cosf(dist * (float)(M_PI / 6.0)) + 1.0f);
        const float cc = (dist < CUTOFF) ? c : 0.0f;
        const float te = __expf(-(5.0f / 6.0f) * dist);
        s_edge[tid] = make_float4(dist, cc, te, 0.0f);
    }
    __syncthreads();

    // ---- Per-thread loop-invariant constants (fixed feature column) ----
    const int col   = tid % COLS;       // float4 column 0..39
    const int eiter = tid / COLS;       // edge slot within an iteration 0..7
    const bool isRBF = (col < NUM_RBF / 4);

    // Reference constants (double-folded)
    const float start = (float)0.0024787521766663585;            // exp(-6)
    const float mstep = (float)((1.0 - 0.0024787521766663585) / (NUM_RBF - 1));
    const float beta  = (float)(1.0 /
        ((2.0 / NUM_RBF * (1.0 - 0.0024787521766663585)) *
         (2.0 / NUM_RBF * (1.0 - 0.0024787521766663585))));      // ~4116.4
    const float gstep = (float)(10.0 / (NUM_GAUSS - 1));
    const float ginv  = 20.48f;                                   // 1/(2*w^2)
    const float LOG2E = 1.4426950408889634f;

    // Centers for this thread's 4 features + sqrt(B*log2e) scale
    const int f0 = col * 4;
    float4 C;
    float SB;
    if (isRBF) {
        C.x = start + (float)(f0 + 0) * mstep;
        C.y = start + (float)(f0 + 1) * mstep;
        C.z = start + (float)(f0 + 2) * mstep;
        C.w = start + (float)(f0 + 3) * mstep;
        SB  = sqrtf(beta * LOG2E);
    } else {
        const int g0 = f0 - NUM_RBF;
        C.x = (float)(g0 + 0) * gstep;
        C.y = (float)(g0 + 1) * gstep;
        C.z = (float)(g0 + 2) * gstep;
        C.w = (float)(g0 + 3) * gstep;
        SB  = sqrtf(ginv * LOG2E);
    }

    // ---- Phase 2: iterate over edges; stores contiguous across the block ----
    float4* out4 = (float4*)(out + (size_t)blockEdge0 * NFEAT);
    #pragma unroll
    for (int k = 0; k < NITER; ++k) {
        const float4 es = s_edge[k * EPI + eiter];  // broadcast read
        const float X = isRBF ? es.z : es.x;        // exp(-alpha*d) or d
        const float A = isRBF ? es.y : 1.0f;        // cutoff or 1
        float4 r;
        {
            const float vx = (X - C.x) * SB;
            const float vy = (X - C.y) * SB;
            const float vz = (X - C.z) * SB;
            const float vw = (X - C.w) * SB;
            r.x = A * fast_exp2(-vx * vx);
            r.y = A * fast_exp2(-vy * vy);
            r.z = A * fast_exp2(-vz * vz);
            r.w = A * fast_exp2(-vw * vw);
        }
        out4[k * BLOCK + tid] = r;
    }
}

extern "C" void kernel_launch(void* const* d_in, const int* in_sizes, int n_in,
                              void* d_out, int out_size, void* d_ws, size_t ws_size,
                              hipStream_t stream) {
    const float* pos  = (const float*)d_in[0];
    const int*   eidx = (const int*)d_in[1];
    float*       out  = (float*)d_out;

    const int nblocks = N_EDGES / EPB;   // 25,000
    edge_feat_kernel<<<nblocks, BLOCK, 0, stream>>>(pos, eidx, out);
}